// Round 8
// baseline (139.760 us; speedup 1.0000x reference)
//
#include <hip/hip_runtime.h>
#include <math.h>

#define DIM     512
#define NNODES  10000
#define NEDGES  200000
#define MPAD    10240   // 160 * 64 (padded so XCD packing is exact)
#define NMB     160     // m-groups of 64
#define NGRP    5       // col groups of 2048 (c >> 11)
#define NB      (NGRP * NNODES)   // 50000 buckets
#define SCAN_N  49                // scan blocks (1024 counters each)
#define GEMM_GRID (NMB * 4)       // 640

// D2 roles (by blockIdx):  [0,49) scan | [49,245) scatter | [245,885) gemm
// (hist moved into prep; counts zeroed by hipMemsetAsync before prep)
#define SCAT_BASE  49
#define SCAT_N     196
#define GEMM_BASE  245
#define FUSE_GRID  (GEMM_BASE + GEMM_GRID)   // 885

using floatx4 = __attribute__((ext_vector_type(4))) float;
using half8   = __attribute__((ext_vector_type(8))) _Float16;
using half2v  = __attribute__((ext_vector_type(2))) _Float16;
typedef unsigned long long ull;

template <int N> struct IC { static constexpr int v = N; };

__device__ inline float dot2acc(half2v a, half2v b, float c) {
#if __has_builtin(__builtin_amdgcn_fdot2)
    return __builtin_amdgcn_fdot2(a, b, c, false);
#else
    return fmaf((float)a[0], (float)b[0], fmaf((float)a[1], (float)b[1], c));
#endif
}

__device__ inline int aload(const int* p) {
    return __hip_atomic_load(p, __ATOMIC_RELAXED, __HIP_MEMORY_SCOPE_AGENT);
}
__device__ inline void astore(int* p, int v) {
    __hip_atomic_store(p, v, __ATOMIC_RELAXED, __HIP_MEMORY_SCOPE_AGENT);
}
// RELAXED poll (R3-proven): agent-scope atomic loads hit the coherence point
// directly; acquire polls invalidate the XCD L2 per-iteration and poisoned
// the whole chip in R2 (gemm 4-5x slower). Ordering: producers drain via
// __syncthreads (vmcnt 0) before signaling; consumers read shared data only
// through agent-scope atomics. Compiler fences stop compile-time reordering.
__device__ inline void waitflag(int* f, int target) {
    while (__hip_atomic_load(f, __ATOMIC_RELAXED, __HIP_MEMORY_SCOPE_AGENT) < target)
        __builtin_amdgcn_s_sleep(8);
    __atomic_signal_fence(__ATOMIC_ACQUIRE);
}
__device__ inline void signal(int* f) {
    __atomic_signal_fence(__ATOMIC_RELEASE);
    __hip_atomic_fetch_add(f, 1, __ATOMIC_RELAXED, __HIP_MEMORY_SCOPE_AGENT);
}

// ---------------------------------------------------------------------------
// prep: fused  (a) Z fp32 -> Zh16 fp16 [MPAD][512] (pad rows zeroed)
//              (b) W fp32 [k][n] -> Wh16t fp16 [n][k] (LDS tile transpose)
//              (c) HIST: bucket histogram of edges (counts pre-zeroed by
//                  hipMemsetAsync -> no intra-kernel ordering needed).
// Moving hist here takes it off gemm_sort's critical chain (R7 diagnosis:
// the hist->scan->scatter chain, not the GEMM, pinned gemm_sort at ~45us).
// ---------------------------------------------------------------------------
#define PREP_ZBLK 2560            // MPAD*512/(256*8)
#define PREP_WBASE PREP_ZBLK      // 64 W-transpose blocks
#define PREP_HBASE (PREP_ZBLK + 64)
#define PREP_HBLK  64
#define PREP_GRID  (PREP_HBASE + PREP_HBLK)   // 2688
__global__ __launch_bounds__(256) void prep(const float* __restrict__ Z,
                                            const float* __restrict__ W,
                                            const int* __restrict__ eidx,
                                            _Float16* __restrict__ Zh16,
                                            _Float16* __restrict__ Wh16t,
                                            int* __restrict__ counts) {
    const int b = blockIdx.x;
    const int t = threadIdx.x;

    if (b < PREP_ZBLK) {
        const int idx8 = (b * 256 + t) * 8;
        const int m = idx8 >> 9;
        float x[8];
        if (m < NNODES) {
            float4 v0 = *(const float4*)(Z + idx8);
            float4 v1 = *(const float4*)(Z + idx8 + 4);
            x[0]=v0.x; x[1]=v0.y; x[2]=v0.z; x[3]=v0.w;
            x[4]=v1.x; x[5]=v1.y; x[6]=v1.z; x[7]=v1.w;
        } else {
            #pragma unroll
            for (int j = 0; j < 8; ++j) x[j] = 0.f;
        }
        half8 h;
        #pragma unroll
        for (int j = 0; j < 8; ++j) h[j] = (_Float16)x[j];
        *(half8*)(Zh16 + idx8) = h;
    } else if (b < PREP_HBASE) {
        __shared__ float tile[64][65];
        const int wb = b - PREP_WBASE;     // 0..63
        const int kb = (wb >> 3) * 64;
        const int nb = (wb & 7) * 64;
        const int kk = t >> 2;
        const int ch = t & 3;

        const float* src = W + (size_t)(kb + kk) * DIM + nb + ch * 16;
        #pragma unroll
        for (int q = 0; q < 4; ++q) {
            float4 v = *(const float4*)(src + q * 4);
            tile[kk][ch * 16 + q * 4 + 0] = v.x;
            tile[kk][ch * 16 + q * 4 + 1] = v.y;
            tile[kk][ch * 16 + q * 4 + 2] = v.z;
            tile[kk][ch * 16 + q * 4 + 3] = v.w;
        }
        __syncthreads();

        const int nn = kk;
        half8 h0, h1;
        #pragma unroll
        for (int i = 0; i < 8; ++i) h0[i] = (_Float16)tile[ch * 16 + i][nn];
        #pragma unroll
        for (int i = 0; i < 8; ++i) h1[i] = (_Float16)tile[ch * 16 + 8 + i][nn];
        _Float16* d = Wh16t + (size_t)(nb + nn) * DIM + kb + ch * 16;
        *(half8*)(d)     = h0;
        *(half8*)(d + 8) = h1;
    } else {
        const int hb = b - PREP_HBASE;     // 0..63
        for (int e = hb * 256 + t; e < NEDGES; e += PREP_HBLK * 256) {
            int r = eidx[e];
            int c = eidx[NEDGES + e];
            atomicAdd(&counts[(c >> 11) * NNODES + r], 1);
        }
    }
}

// ---------------------------------------------------------------------------
// D2: fused sort-finish + GEMM. counts are FINAL at dispatch (hist ran in
// prep), so scan starts immediately; scatter (196 blocks, 2x R7) waits only
// for cursor and emits ONE packed 8B slot per edge (key | row<<32) -- half
// the scattered lines / RMW traffic of the old 4B+2B pair.
// GEMM: R7's counted-vmcnt 2-deep pipeline + R6 XCD packing (kept).
// flags[1]: scan-local done (49); flags[2]: cursor ready (49).
// ---------------------------------------------------------------------------
__global__ __launch_bounds__(256, 3) void gemm_sort(
        const _Float16* __restrict__ Zh16,
        const _Float16* __restrict__ Wh16t,
        _Float16* __restrict__ ZWh,
        const int* __restrict__ eidx,
        int* __restrict__ counts,
        int* __restrict__ cursor,
        int* __restrict__ blksum,
        ull* __restrict__ slots,
        int* __restrict__ flags)
{
    __shared__ _Float16 Abuf[2][2 * 64 * 32];    // 16 KB
    __shared__ _Float16 Bbuf[2][2 * 128 * 32];   // 32 KB
    __shared__ int wsum[4];
    __shared__ int sbase;

    const int t   = threadIdx.x;
    const int bid = blockIdx.x;

    // ---------------- role: GEMM (no waits on flags) ----------------
    if (bid >= GEMM_BASE) {
        const int s8  = bid - GEMM_BASE;      // 0..639
        const int cxd = bid & 7;              // XCD class (bid%8 -> XCD)
        const int rr  = s8 >> 3;              // 0..79
        const int mg  = (rr >> 2) * 8 + cxd;  // 0..159, same-m => same XCD
        const int m0  = mg * 64;
        const int n0  = (rr & 3) * 128;

        const int l  = t & 63;
        const int w  = t >> 6;
        const int wn = w * 32;
        const int lm = l & 15;
        const int lq = l >> 4;
        const unsigned wbase = (unsigned)(t & 192);

        floatx4 acc[4][2] = {};

        auto stage = [&](int buf, int k0) {    // 6 global_load_lds / thread
            #pragma unroll
            for (int p = 0; p < 2; ++p) {
                const int s   = p * 256 + t;
                const int kk  = s >> 8;
                const int row = (s >> 2) & 63;
                const int ch  = s & 3;
                const _Float16* src = Zh16 + (size_t)(m0 + row) * DIM + k0 + kk * 32 + ch * 8;
                __builtin_amdgcn_global_load_lds(
                    (const __attribute__((address_space(1))) void*)src,
                    (__attribute__((address_space(3))) void*)&Abuf[buf][(p * 256 + wbase) * 8],
                    16, 0, 0);
            }
            #pragma unroll
            for (int p = 0; p < 4; ++p) {
                const int s   = p * 256 + t;
                const int kk  = s >> 9;
                const int row = (s >> 2) & 127;
                const int ch  = s & 3;
                const _Float16* src = Wh16t + (size_t)(n0 + row) * DIM + k0 + kk * 32 + ch * 8;
                __builtin_amdgcn_global_load_lds(
                    (const __attribute__((address_space(1))) void*)src,
                    (__attribute__((address_space(3))) void*)&Bbuf[buf][(p * 256 + wbase) * 8],
                    16, 0, 0);
            }
        };

        stage(0, 0);
        stage(1, 64);          // 12 loads in flight

        auto step = [&](auto Sc) {
            constexpr int S   = decltype(Sc)::v;
            constexpr int buf = S & 1;
            // stage(S) complete; stage(S+1)'s 6 loads stay in flight
            if constexpr (S < 7) asm volatile("s_waitcnt vmcnt(6)" ::: "memory");
            else                 asm volatile("s_waitcnt vmcnt(0)" ::: "memory");
            __builtin_amdgcn_sched_barrier(0);
            __builtin_amdgcn_s_barrier();          // all waves' stage(S) landed
            __builtin_amdgcn_sched_barrier(0);

            half8 aF[2][4], bF[2][2];
            #pragma unroll
            for (int kk = 0; kk < 2; ++kk) {
                #pragma unroll
                for (int i = 0; i < 4; ++i)
                    aF[kk][i] = *(const half8*)&Abuf[buf][kk * 2048 + (16 * i + lm) * 32 + lq * 8];
                #pragma unroll
                for (int j = 0; j < 2; ++j)
                    bF[kk][j] = *(const half8*)&Bbuf[buf][kk * 4096 + (wn + 16 * j + lm) * 32 + lq * 8];
            }
            asm volatile("s_waitcnt lgkmcnt(0)" ::: "memory");
            __builtin_amdgcn_sched_barrier(0);
            __builtin_amdgcn_s_barrier();          // WAR: all waves read buf
            __builtin_amdgcn_sched_barrier(0);

            if constexpr (S < 6) stage(buf, (S + 2) * 64);   // refill freed buf

            #pragma unroll
            for (int kk = 0; kk < 2; ++kk)
                #pragma unroll
                for (int i = 0; i < 4; ++i)
                    #pragma unroll
                    for (int j = 0; j < 2; ++j)
                        acc[i][j] = __builtin_amdgcn_mfma_f32_16x16x32_f16(
                            aF[kk][i], bF[kk][j], acc[i][j], 0, 0, 0);
        };

        step(IC<0>{}); step(IC<1>{}); step(IC<2>{}); step(IC<3>{});
        step(IC<4>{}); step(IC<5>{}); step(IC<6>{}); step(IC<7>{});

        #pragma unroll
        for (int i = 0; i < 4; ++i)
            #pragma unroll
            for (int j = 0; j < 2; ++j)
                #pragma unroll
                for (int r = 0; r < 4; ++r) {
                    const int gm = m0 + 16 * i + lq * 4 + r;
                    const int gn = n0 + wn + 16 * j + lm;
                    if (gm < NNODES)
                        ZWh[(size_t)gm * DIM + gn] = (_Float16)acc[i][j][r];
                }
        return;
    }

    // ---------------- role: scan (starts immediately; counts final) --------
    if (bid < SCAT_BASE) {
        const int b = bid;                   // 0..48
        const int lane = t & 63;
        const int wv   = t >> 6;

        const int base = b * 1024 + t * 4;
        int v0 = 0, v1 = 0, v2 = 0, v3 = 0;
        if (base + 3 < NB) {
            v0 = aload(counts + base);
            v1 = aload(counts + base + 1);
            v2 = aload(counts + base + 2);
            v3 = aload(counts + base + 3);
        } else {
            if (base     < NB) v0 = aload(counts + base);
            if (base + 1 < NB) v1 = aload(counts + base + 1);
            if (base + 2 < NB) v2 = aload(counts + base + 2);
        }
        const int ts = v0 + v1 + v2 + v3;
        int incl = ts;
        #pragma unroll
        for (int off = 1; off < 64; off <<= 1) {
            int u = __shfl_up(incl, off, 64);
            if (lane >= off) incl += u;
        }
        if (lane == 63) wsum[wv] = incl;
        __syncthreads();
        int wb = 0;
        #pragma unroll
        for (int k = 0; k < 4; ++k) if (k < wv) wb += wsum[k];
        const int ex   = wb + incl - ts;
        const int pre0 = ex;
        const int pre1 = ex + v0;
        const int pre2 = pre1 + v1;
        const int pre3 = pre2 + v2;
        if (t == 255) astore(blksum + b, wb + incl);
        __syncthreads();                       // vmcnt(0): blksum store visible
        if (t == 0) { signal(&flags[1]); waitflag(&flags[1], SCAN_N); }
        __syncthreads();

        if (t < 64) {
            int v = (t < b) ? aload(blksum + t) : 0;
            #pragma unroll
            for (int off = 32; off > 0; off >>= 1)
                v += __shfl_xor(v, off, 64);
            if (t == 0) sbase = v;
        }
        __syncthreads();
        const int b0 = sbase;

        if (base + 3 < NB) {
            astore(cursor + base,     b0 + pre0);
            astore(cursor + base + 1, b0 + pre1);
            astore(cursor + base + 2, b0 + pre2);
            astore(cursor + base + 3, b0 + pre3);
        } else {
            if (base     < NB) astore(cursor + base,     b0 + pre0);
            if (base + 1 < NB) astore(cursor + base + 1, b0 + pre1);
            if (base + 2 < NB) astore(cursor + base + 2, b0 + pre2);
        }
        __syncthreads();                       // vmcnt(0): cursor stores visible
        if (t == 0) signal(&flags[2]);
        return;
    }

    // ---------------- role: scatter (waits for cursor; packed 8B slot) -----
    {
        if (t == 0) waitflag(&flags[2], SCAN_N);
        __syncthreads();

        for (int e = (bid - SCAT_BASE) * 256 + t; e < NEDGES; e += SCAT_N * 256) {
            int r = eidx[e];
            int c = eidx[NEDGES + e];
            int pos = atomicAdd(&cursor[(c >> 11) * NNODES + r], 1);
            slots[pos] = (ull)(((unsigned)c << 18) | (unsigned)e) | ((ull)(unsigned)r << 32);
        }
    }
}

// ---------------------------------------------------------------------------
// Edge scoring (flat): wave w handles edges 4w..4w+3 of the sorted array.
// 16 lanes/edge; one packed 8B slot read; 8 independent b128 row loads.
// ---------------------------------------------------------------------------
__global__ __launch_bounds__(256) void edge_score_f(const _Float16* __restrict__ ZWh,
                                                    const _Float16* __restrict__ Zh,
                                                    const ull* __restrict__ slots,
                                                    float* __restrict__ out) {
    const int t    = threadIdx.x;
    const int wgid = blockIdx.x * 4 + (t >> 6);
    const int lane = t & 63;
    const int gq   = lane >> 4;
    const int sl   = lane & 15;

    const int ii = wgid * 4 + gq;
    const ull  v = slots[ii];
    const unsigned k = (unsigned)v;
    const int c = (int)(k >> 18);
    const int r = (int)((v >> 32) & 0xFFFFu);

    const _Float16* rp = ZWh + (size_t)r * DIM + sl * 32;
    const _Float16* cp = Zh  + (size_t)c * DIM + sl * 32;

    half8 ra0 = *(const half8*)(rp);
    half8 ra1 = *(const half8*)(rp + 8);
    half8 ra2 = *(const half8*)(rp + 16);
    half8 ra3 = *(const half8*)(rp + 24);
    half8 c0  = *(const half8*)(cp);
    half8 c1  = *(const half8*)(cp + 8);
    half8 c2  = *(const half8*)(cp + 16);
    half8 c3  = *(const half8*)(cp + 24);

    float s = 0.f;
    #pragma unroll
    for (int d = 0; d < 4; ++d) {
        s = dot2acc((half2v){ra0[2*d], ra0[2*d+1]}, (half2v){c0[2*d], c0[2*d+1]}, s);
        s = dot2acc((half2v){ra1[2*d], ra1[2*d+1]}, (half2v){c1[2*d], c1[2*d+1]}, s);
        s = dot2acc((half2v){ra2[2*d], ra2[2*d+1]}, (half2v){c2[2*d], c2[2*d+1]}, s);
        s = dot2acc((half2v){ra3[2*d], ra3[2*d+1]}, (half2v){c3[2*d], c3[2*d+1]}, s);
    }

    s += __shfl_xor(s, 1, 64);
    s += __shfl_xor(s, 2, 64);
    s += __shfl_xor(s, 4, 64);
    s += __shfl_xor(s, 8, 64);

    if (sl == 0)
        out[k & 0x3FFFFu] = 1.0f / (1.0f + expf(-s));
}

// ---------------------------------------------------------------------------
// fp32 fallback path (ws too small)
// ---------------------------------------------------------------------------
#define GTM 128
#define GTN 64
#define GTK 16
#define LDA 132
#define LDB 68

__global__ __launch_bounds__(256) void gemm_zw(const float* __restrict__ A,
                                               const float* __restrict__ B,
                                               float* __restrict__ C) {
    __shared__ float As[GTK * LDA];
    __shared__ float Bs[GTK * LDB];

    const int t  = threadIdx.x;
    const int m0 = blockIdx.x * GTM;
    const int n0 = blockIdx.y * GTN;
    const int tx = t & 15;
    const int ty = t >> 4;

    float acc[8][4] = {};

    for (int k0 = 0; k0 < DIM; k0 += GTK) {
        #pragma unroll
        for (int p = 0; p < 2; ++p) {
            int f  = t + p * 256;
            int mm = f >> 2;
            int kq = f & 3;
            int m  = m0 + mm;
            float4 v = make_float4(0.f, 0.f, 0.f, 0.f);
            if (m < NNODES)
                v = *(const float4*)(A + (size_t)m * DIM + k0 + kq * 4);
            As[(kq * 4 + 0) * LDA + mm] = v.x;
            As[(kq * 4 + 1) * LDA + mm] = v.y;
            As[(kq * 4 + 2) * LDA + mm] = v.z;
            As[(kq * 4 + 3) * LDA + mm] = v.w;
        }
        {
            int kb = t >> 4, n4 = t & 15;
            *(float4*)&Bs[kb * LDB + n4 * 4] =
                *(const float4*)(B + (size_t)(k0 + kb) * DIM + n0 + n4 * 4);
        }
        __syncthreads();

        #pragma unroll
        for (int kk = 0; kk < GTK; ++kk) {
            float4 a0 = *(const float4*)&As[kk * LDA + ty * 8];
            float4 a1 = *(const float4*)&As[kk * LDA + ty * 8 + 4];
            float4 b  = *(const float4*)&Bs[kk * LDB + tx * 4];
            float av[8] = {a0.x, a0.y, a0.z, a0.w, a1.x, a1.y, a1.z, a1.w};
            float bv[4] = {b.x, b.y, b.z, b.w};
            #pragma unroll
            for (int i = 0; i < 8; ++i)
                #pragma unroll
                for (int j = 0; j < 4; ++j)
                    acc[i][j] = fmaf(av[i], bv[j], acc[i][j]);
        }
        __syncthreads();
    }

    #pragma unroll
    for (int i = 0; i < 8; ++i) {
        int m = m0 + ty * 8 + i;
        if (m < NNODES)
            *(float4*)(C + (size_t)m * DIM + n0 + tx * 4) =
                make_float4(acc[i][0], acc[i][1], acc[i][2], acc[i][3]);
    }
}

__global__ __launch_bounds__(256) void edge_score(const float* __restrict__ ZW,
                                                  const float* __restrict__ Z,
                                                  const int* __restrict__ eidx,
                                                  float* __restrict__ out) {
    const int e    = blockIdx.x * 4 + (threadIdx.x >> 6);
    const int lane = threadIdx.x & 63;

    const int r = eidx[e];
    const int c = eidx[NEDGES + e];

    const float4* pr = (const float4*)(ZW + (size_t)r * DIM);
    const float4* pc = (const float4*)(Z  + (size_t)c * DIM);

    float4 a0 = pr[lane * 2 + 0];
    float4 a1 = pr[lane * 2 + 1];
    float4 b0 = pc[lane * 2 + 0];
    float4 b1 = pc[lane * 2 + 1];

    float s = a0.x * b0.x;
    s = fmaf(a0.y, b0.y, s);
    s = fmaf(a0.z, b0.z, s);
    s = fmaf(a0.w, b0.w, s);
    s = fmaf(a1.x, b1.x, s);
    s = fmaf(a1.y, b1.y, s);
    s = fmaf(a1.z, b1.z, s);
    s = fmaf(a1.w, b1.w, s);

    #pragma unroll
    for (int off = 32; off > 0; off >>= 1)
        s += __shfl_xor(s, off, 64);

    if (lane == 0)
        out[e] = 1.0f / (1.0f + expf(-s));
}

// ---------------------------------------------------------------------------
extern "C" void kernel_launch(void* const* d_in, const int* in_sizes, int n_in,
                              void* d_out, int out_size, void* d_ws, size_t ws_size,
                              hipStream_t stream) {
    const float* Z  = (const float*)d_in[0];
    const float* W  = (const float*)d_in[1];
    const int*   EI = (const int*)d_in[2];
    float* out = (float*)d_out;

    char* p = (char*)d_ws;
    _Float16* ZWh   = (_Float16*)p;  p += (size_t)MPAD * DIM * 2;
    _Float16* Zh16  = (_Float16*)p;  p += (size_t)MPAD * DIM * 2;
    _Float16* Wh16t = (_Float16*)p;  p += (size_t)DIM * DIM * 2;
    int* counts  = (int*)p;          p += (size_t)NB * 4;
    int* flags   = (int*)p;          p += 4 * 4;          // adjacent: one memset
    int* cursor  = (int*)p;          p += (size_t)NB * 4;
    int* blksum  = (int*)p;          p += (size_t)SCAN_N * 4;
    ull* slots   = (ull*)p;          p += (size_t)NEDGES * 8;
    const size_t need_full = (size_t)(p - (char*)d_ws);

    if (ws_size >= need_full) {
        // zero counts+flags (capture-legal; removes hist ordering dependency)
        hipMemsetAsync(counts, 0, (size_t)NB * 4 + 16, stream);
        prep<<<PREP_GRID, 256, 0, stream>>>(Z, W, EI, Zh16, Wh16t, counts);
        gemm_sort<<<FUSE_GRID, 256, 0, stream>>>(Zh16, Wh16t, ZWh, EI, counts,
                                                 cursor, blksum, slots, flags);
        edge_score_f<<<NEDGES / 16, 256, 0, stream>>>(ZWh, Zh16, slots, out);
    } else {
        float* ZW = (float*)d_ws;
        dim3 g1((NNODES + GTM - 1) / GTM, DIM / GTN);
        gemm_zw<<<g1, 256, 0, stream>>>(Z, W, ZW);
        edge_score<<<NEDGES / 4, 256, 0, stream>>>(ZW, Z, EI, out);
    }
}

// Round 9
// 128.663 us; speedup vs baseline: 1.0862x; 1.0862x over previous
//
#include <hip/hip_runtime.h>
#include <math.h>

#define DIM     512
#define NNODES  10000
#define NEDGES  200000
#define MPAD    10240   // 160 * 64 (padded so XCD packing is exact)
#define NMB     160     // m-groups of 64
#define GEMM_GRID (NMB * 4)       // 640 pure-GEMM blocks

using floatx4 = __attribute__((ext_vector_type(4))) float;
using half8   = __attribute__((ext_vector_type(8))) _Float16;
using half2v  = __attribute__((ext_vector_type(2))) _Float16;

template <int N> struct IC { static constexpr int v = N; };

__device__ inline float dot2acc(half2v a, half2v b, float c) {
#if __has_builtin(__builtin_amdgcn_fdot2)
    return __builtin_amdgcn_fdot2(a, b, c, false);
#else
    return fmaf((float)a[0], (float)b[0], fmaf((float)a[1], (float)b[1], c));
#endif
}

// ---------------------------------------------------------------------------
// prep: (a) Z fp32 -> Zh16 fp16 [MPAD][512] (pad rows zeroed)
//       (b) W fp32 [k][n] -> Wh16t fp16 [n][k] (LDS tile transpose)
// R9: the whole sort apparatus (hist/scan/scatter/slots/flags/memset) is
// DELETED -- the gather tables are 21 MB (fully L3-resident), so sorted
// order bought ~5us of locality for ~25-30us of sort cost (R3-R8 ablations:
// gemm_sort pinned at ~44us through three GEMM rewrites; the sort was the
// only invariant).
// ---------------------------------------------------------------------------
#define PREP_ZBLK 2560            // MPAD*512/(256*8)
#define PREP_GRID (PREP_ZBLK + 64)
__global__ __launch_bounds__(256) void prep(const float* __restrict__ Z,
                                            const float* __restrict__ W,
                                            _Float16* __restrict__ Zh16,
                                            _Float16* __restrict__ Wh16t) {
    const int b = blockIdx.x;
    const int t = threadIdx.x;

    if (b < PREP_ZBLK) {
        const int idx8 = (b * 256 + t) * 8;
        const int m = idx8 >> 9;
        float x[8];
        if (m < NNODES) {
            float4 v0 = *(const float4*)(Z + idx8);
            float4 v1 = *(const float4*)(Z + idx8 + 4);
            x[0]=v0.x; x[1]=v0.y; x[2]=v0.z; x[3]=v0.w;
            x[4]=v1.x; x[5]=v1.y; x[6]=v1.z; x[7]=v1.w;
        } else {
            #pragma unroll
            for (int j = 0; j < 8; ++j) x[j] = 0.f;
        }
        half8 h;
        #pragma unroll
        for (int j = 0; j < 8; ++j) h[j] = (_Float16)x[j];
        *(half8*)(Zh16 + idx8) = h;
    } else {
        __shared__ float tile[64][65];
        const int wb = b - PREP_ZBLK;      // 0..63
        const int kb = (wb >> 3) * 64;
        const int nb = (wb & 7) * 64;
        const int kk = t >> 2;
        const int ch = t & 3;

        const float* src = W + (size_t)(kb + kk) * DIM + nb + ch * 16;
        #pragma unroll
        for (int q = 0; q < 4; ++q) {
            float4 v = *(const float4*)(src + q * 4);
            tile[kk][ch * 16 + q * 4 + 0] = v.x;
            tile[kk][ch * 16 + q * 4 + 1] = v.y;
            tile[kk][ch * 16 + q * 4 + 2] = v.z;
            tile[kk][ch * 16 + q * 4 + 3] = v.w;
        }
        __syncthreads();

        const int nn = kk;
        half8 h0, h1;
        #pragma unroll
        for (int i = 0; i < 8; ++i) h0[i] = (_Float16)tile[ch * 16 + i][nn];
        #pragma unroll
        for (int i = 0; i < 8; ++i) h1[i] = (_Float16)tile[ch * 16 + 8 + i][nn];
        _Float16* d = Wh16t + (size_t)(nb + nn) * DIM + kb + ch * 16;
        *(half8*)(d)     = h0;
        *(half8*)(d + 8) = h1;
    }
}

// ---------------------------------------------------------------------------
// Pure GEMM: 64x128 tiles, counted-vmcnt 2-deep pipeline (R7) + XCD packing
// (R6). Grid 640 @ 3 blocks/CU -> all blocks resident, single generation.
// First clean measurement of the GEMM with zero co-resident sort work.
// ---------------------------------------------------------------------------
__global__ __launch_bounds__(256, 3) void gemm_f16(
        const _Float16* __restrict__ Zh16,
        const _Float16* __restrict__ Wh16t,
        _Float16* __restrict__ ZWh)
{
    __shared__ _Float16 Abuf[2][2 * 64 * 32];    // 16 KB
    __shared__ _Float16 Bbuf[2][2 * 128 * 32];   // 32 KB

    const int t   = threadIdx.x;
    const int bid = blockIdx.x;

    const int cxd = bid & 7;              // XCD class (bid%8 -> XCD)
    const int rr  = bid >> 3;             // 0..79
    const int mg  = (rr >> 2) * 8 + cxd;  // 0..159, same-m => same XCD
    const int m0  = mg * 64;
    const int n0  = (rr & 3) * 128;

    const int l  = t & 63;
    const int w  = t >> 6;
    const int wn = w * 32;
    const int lm = l & 15;
    const int lq = l >> 4;
    const unsigned wbase = (unsigned)(t & 192);

    floatx4 acc[4][2] = {};

    auto stage = [&](int buf, int k0) {    // 6 global_load_lds / thread
        #pragma unroll
        for (int p = 0; p < 2; ++p) {
            const int s   = p * 256 + t;
            const int kk  = s >> 8;
            const int row = (s >> 2) & 63;
            const int ch  = s & 3;
            const _Float16* src = Zh16 + (size_t)(m0 + row) * DIM + k0 + kk * 32 + ch * 8;
            __builtin_amdgcn_global_load_lds(
                (const __attribute__((address_space(1))) void*)src,
                (__attribute__((address_space(3))) void*)&Abuf[buf][(p * 256 + wbase) * 8],
                16, 0, 0);
        }
        #pragma unroll
        for (int p = 0; p < 4; ++p) {
            const int s   = p * 256 + t;
            const int kk  = s >> 9;
            const int row = (s >> 2) & 127;
            const int ch  = s & 3;
            const _Float16* src = Wh16t + (size_t)(n0 + row) * DIM + k0 + kk * 32 + ch * 8;
            __builtin_amdgcn_global_load_lds(
                (const __attribute__((address_space(1))) void*)src,
                (__attribute__((address_space(3))) void*)&Bbuf[buf][(p * 256 + wbase) * 8],
                16, 0, 0);
        }
    };

    stage(0, 0);
    stage(1, 64);          // 12 loads in flight

    auto step = [&](auto Sc) {
        constexpr int S   = decltype(Sc)::v;
        constexpr int buf = S & 1;
        // stage(S) complete; stage(S+1)'s 6 loads stay in flight
        if constexpr (S < 7) asm volatile("s_waitcnt vmcnt(6)" ::: "memory");
        else                 asm volatile("s_waitcnt vmcnt(0)" ::: "memory");
        __builtin_amdgcn_sched_barrier(0);
        __builtin_amdgcn_s_barrier();          // all waves' stage(S) landed
        __builtin_amdgcn_sched_barrier(0);

        half8 aF[2][4], bF[2][2];
        #pragma unroll
        for (int kk = 0; kk < 2; ++kk) {
            #pragma unroll
            for (int i = 0; i < 4; ++i)
                aF[kk][i] = *(const half8*)&Abuf[buf][kk * 2048 + (16 * i + lm) * 32 + lq * 8];
            #pragma unroll
            for (int j = 0; j < 2; ++j)
                bF[kk][j] = *(const half8*)&Bbuf[buf][kk * 4096 + (wn + 16 * j + lm) * 32 + lq * 8];
        }
        asm volatile("s_waitcnt lgkmcnt(0)" ::: "memory");
        __builtin_amdgcn_sched_barrier(0);
        __builtin_amdgcn_s_barrier();          // WAR: all waves read buf
        __builtin_amdgcn_sched_barrier(0);

        if constexpr (S < 6) stage(buf, (S + 2) * 64);   // refill freed buf

        #pragma unroll
        for (int kk = 0; kk < 2; ++kk)
            #pragma unroll
            for (int i = 0; i < 4; ++i)
                #pragma unroll
                for (int j = 0; j < 2; ++j)
                    acc[i][j] = __builtin_amdgcn_mfma_f32_16x16x32_f16(
                        aF[kk][i], bF[kk][j], acc[i][j], 0, 0, 0);
    };

    step(IC<0>{}); step(IC<1>{}); step(IC<2>{}); step(IC<3>{});
    step(IC<4>{}); step(IC<5>{}); step(IC<6>{}); step(IC<7>{});

    #pragma unroll
    for (int i = 0; i < 4; ++i)
        #pragma unroll
        for (int j = 0; j < 2; ++j)
            #pragma unroll
            for (int r = 0; r < 4; ++r) {
                const int gm = m0 + 16 * i + lq * 4 + r;
                const int gn = n0 + wn + 16 * j + lm;
                if (gm < NNODES)
                    ZWh[(size_t)gm * DIM + gn] = (_Float16)acc[i][j][r];
            }
}

// ---------------------------------------------------------------------------
// Edge scoring, UNSORTED: wave handles 4 edges straight from eidx; 16 lanes
// per edge; 8 independent b128 loads per lane. Tables are 21 MB total ->
// fully L3-resident, so random order costs only marginal locality while the
// output write becomes contiguous (out[e], was scattered via the sort key).
// ---------------------------------------------------------------------------
__global__ __launch_bounds__(256) void edge_score_u(const _Float16* __restrict__ ZWh,
                                                    const _Float16* __restrict__ Zh,
                                                    const int* __restrict__ eidx,
                                                    float* __restrict__ out) {
    const int t    = threadIdx.x;
    const int lane = t & 63;
    const int gq   = lane >> 4;
    const int sl   = lane & 15;

    const int e = blockIdx.x * 16 + (t >> 6) * 4 + gq;
    const int r = eidx[e];
    const int c = eidx[NEDGES + e];

    const _Float16* rp = ZWh + (size_t)r * DIM + sl * 32;
    const _Float16* cp = Zh  + (size_t)c * DIM + sl * 32;

    half8 ra0 = *(const half8*)(rp);
    half8 ra1 = *(const half8*)(rp + 8);
    half8 ra2 = *(const half8*)(rp + 16);
    half8 ra3 = *(const half8*)(rp + 24);
    half8 c0  = *(const half8*)(cp);
    half8 c1  = *(const half8*)(cp + 8);
    half8 c2  = *(const half8*)(cp + 16);
    half8 c3  = *(const half8*)(cp + 24);

    float s = 0.f;
    #pragma unroll
    for (int d = 0; d < 4; ++d) {
        s = dot2acc((half2v){ra0[2*d], ra0[2*d+1]}, (half2v){c0[2*d], c0[2*d+1]}, s);
        s = dot2acc((half2v){ra1[2*d], ra1[2*d+1]}, (half2v){c1[2*d], c1[2*d+1]}, s);
        s = dot2acc((half2v){ra2[2*d], ra2[2*d+1]}, (half2v){c2[2*d], c2[2*d+1]}, s);
        s = dot2acc((half2v){ra3[2*d], ra3[2*d+1]}, (half2v){c3[2*d], c3[2*d+1]}, s);
    }

    s += __shfl_xor(s, 1, 64);
    s += __shfl_xor(s, 2, 64);
    s += __shfl_xor(s, 4, 64);
    s += __shfl_xor(s, 8, 64);

    if (sl == 0)
        out[e] = 1.0f / (1.0f + expf(-s));
}

// ---------------------------------------------------------------------------
// fp32 fallback path (ws too small)
// ---------------------------------------------------------------------------
#define GTM 128
#define GTN 64
#define GTK 16
#define LDA 132
#define LDB 68

__global__ __launch_bounds__(256) void gemm_zw(const float* __restrict__ A,
                                               const float* __restrict__ B,
                                               float* __restrict__ C) {
    __shared__ float As[GTK * LDA];
    __shared__ float Bs[GTK * LDB];

    const int t  = threadIdx.x;
    const int m0 = blockIdx.x * GTM;
    const int n0 = blockIdx.y * GTN;
    const int tx = t & 15;
    const int ty = t >> 4;

    float acc[8][4] = {};

    for (int k0 = 0; k0 < DIM; k0 += GTK) {
        #pragma unroll
        for (int p = 0; p < 2; ++p) {
            int f  = t + p * 256;
            int mm = f >> 2;
            int kq = f & 3;
            int m  = m0 + mm;
            float4 v = make_float4(0.f, 0.f, 0.f, 0.f);
            if (m < NNODES)
                v = *(const float4*)(A + (size_t)m * DIM + k0 + kq * 4);
            As[(kq * 4 + 0) * LDA + mm] = v.x;
            As[(kq * 4 + 1) * LDA + mm] = v.y;
            As[(kq * 4 + 2) * LDA + mm] = v.z;
            As[(kq * 4 + 3) * LDA + mm] = v.w;
        }
        {
            int kb = t >> 4, n4 = t & 15;
            *(float4*)&Bs[kb * LDB + n4 * 4] =
                *(const float4*)(B + (size_t)(k0 + kb) * DIM + n0 + n4 * 4);
        }
        __syncthreads();

        #pragma unroll
        for (int kk = 0; kk < GTK; ++kk) {
            float4 a0 = *(const float4*)&As[kk * LDA + ty * 8];
            float4 a1 = *(const float4*)&As[kk * LDA + ty * 8 + 4];
            float4 b  = *(const float4*)&Bs[kk * LDB + tx * 4];
            float av[8] = {a0.x, a0.y, a0.z, a0.w, a1.x, a1.y, a1.z, a1.w};
            float bv[4] = {b.x, b.y, b.z, b.w};
            #pragma unroll
            for (int i = 0; i < 8; ++i)
                #pragma unroll
                for (int j = 0; j < 4; ++j)
                    acc[i][j] = fmaf(av[i], bv[j], acc[i][j]);
        }
        __syncthreads();
    }

    #pragma unroll
    for (int i = 0; i < 8; ++i) {
        int m = m0 + ty * 8 + i;
        if (m < NNODES)
            *(float4*)(C + (size_t)m * DIM + n0 + tx * 4) =
                make_float4(acc[i][0], acc[i][1], acc[i][2], acc[i][3]);
    }
}

__global__ __launch_bounds__(256) void edge_score(const float* __restrict__ ZW,
                                                  const float* __restrict__ Z,
                                                  const int* __restrict__ eidx,
                                                  float* __restrict__ out) {
    const int e    = blockIdx.x * 4 + (threadIdx.x >> 6);
    const int lane = threadIdx.x & 63;

    const int r = eidx[e];
    const int c = eidx[NEDGES + e];

    const float4* pr = (const float4*)(ZW + (size_t)r * DIM);
    const float4* pc = (const float4*)(Z  + (size_t)c * DIM);

    float4 a0 = pr[lane * 2 + 0];
    float4 a1 = pr[lane * 2 + 1];
    float4 b0 = pc[lane * 2 + 0];
    float4 b1 = pc[lane * 2 + 1];

    float s = a0.x * b0.x;
    s = fmaf(a0.y, b0.y, s);
    s = fmaf(a0.z, b0.z, s);
    s = fmaf(a0.w, b0.w, s);
    s = fmaf(a1.x, b1.x, s);
    s = fmaf(a1.y, b1.y, s);
    s = fmaf(a1.z, b1.z, s);
    s = fmaf(a1.w, b1.w, s);

    #pragma unroll
    for (int off = 32; off > 0; off >>= 1)
        s += __shfl_xor(s, off, 64);

    if (lane == 0)
        out[e] = 1.0f / (1.0f + expf(-s));
}

// ---------------------------------------------------------------------------
extern "C" void kernel_launch(void* const* d_in, const int* in_sizes, int n_in,
                              void* d_out, int out_size, void* d_ws, size_t ws_size,
                              hipStream_t stream) {
    const float* Z  = (const float*)d_in[0];
    const float* W  = (const float*)d_in[1];
    const int*   EI = (const int*)d_in[2];
    float* out = (float*)d_out;

    char* p = (char*)d_ws;
    _Float16* ZWh   = (_Float16*)p;  p += (size_t)MPAD * DIM * 2;
    _Float16* Zh16  = (_Float16*)p;  p += (size_t)MPAD * DIM * 2;
    _Float16* Wh16t = (_Float16*)p;  p += (size_t)DIM * DIM * 2;
    const size_t need_full = (size_t)(p - (char*)d_ws);

    if (ws_size >= need_full) {
        prep<<<PREP_GRID, 256, 0, stream>>>(Z, W, Zh16, Wh16t);
        gemm_f16<<<GEMM_GRID, 256, 0, stream>>>(Zh16, Wh16t, ZWh);
        edge_score_u<<<NEDGES / 16, 256, 0, stream>>>(ZWh, Zh16, EI, out);
    } else {
        float* ZW = (float*)d_ws;
        dim3 g1((NNODES + GTM - 1) / GTM, DIM / GTN);
        gemm_zw<<<g1, 256, 0, stream>>>(Z, W, ZW);
        edge_score<<<NEDGES / 4, 256, 0, stream>>>(ZW, Z, EI, out);
    }
}